// Round 12
// baseline (18.033 us; speedup 1.0000x reference)
//
#include <hip/hip_runtime.h>
#include <math.h>

// field[c,x,y] = sum_n exp(-(x-xc[n])^2/(2s^2)) * exp(-(y-yc[n])^2/(2s^2)) * v[c,n]
// v = init_vectors * (32/(W+L)), s = 32. Output [1,2,W,L] fp32, y fastest.
//
// R11: R10 (nt stores, 15.2us) with ONE change: TX 32->16 -> grid 4096 =
// 2 occupancy rounds (8 blocks/CU resident). Round-2 compute overlaps
// round-1's store drain — with grid==residency (all prior rounds) every
// block stored at the same time and the 5.3us drain serialized after
// compute. Thread now owns 1x x 4y; ex is a scalar broadcast.

#define N_MAX  512
#define TX     16
#define TY     64
#define R_CUT  128.0f
#define BATCH  8

#define EXP2F(x) __builtin_amdgcn_exp2f(x)

typedef float f4 __attribute__((ext_vector_type(4)));

__global__ __launch_bounds__(256, 8) void motion_field_kernel(
    const float* __restrict__ init_vectors,  // [2, N]
    const int*   __restrict__ x_coord,       // [N]
    const int*   __restrict__ y_coord,       // [N]
    const int*   __restrict__ d_width,       // [1]
    const int*   __restrict__ d_lenth,       // [1]
    float*       __restrict__ out,           // [2, W, L]
    int N, int W, int L)
{
    __shared__ float s_xc[N_MAX], s_yc[N_MAX], s_v0[N_MAX], s_v1[N_MAX];
    __shared__ short s_list[N_MAX];
    __shared__ int   s_cnt[4];
    __shared__ float s_ex[BATCH][TX];
    __shared__ float s_ey[BATCH][TY];

    const int tid  = threadIdx.x;
    const int wave = tid >> 6;
    const int lane = tid & 63;

    const float scale = 32.0f / (float)(d_width[0] + d_lenth[0]);  // MAGNITUDE=1

    for (int i = tid; i < N; i += 256) {
        s_xc[i] = (float)x_coord[i];
        s_yc[i] = (float)y_coord[i];
        s_v0[i] = init_vectors[i] * scale;
        s_v1[i] = init_vectors[N + i] * scale;
    }
    __syncthreads();

    const int x0 = blockIdx.x * TX;
    const int y0 = blockIdx.y * TY;
    const float bx_lo = (float)x0 - R_CUT;
    const float bx_hi = (float)(x0 + TX - 1) + R_CUT;
    const float by_lo = (float)y0 - R_CUT;
    const float by_hi = (float)(y0 + TY - 1) + R_CUT;

    // ---- wave-parallel scan + deterministic ballot compaction ----
    int total = 0;
    for (int base_n = 0; base_n < N; base_n += 256) {
        const int n = base_n + tid;
        bool pred = false;
        if (n < N) {
            const float xc = s_xc[n], yc = s_yc[n];
            pred = (xc >= bx_lo) && (xc <= bx_hi) && (yc >= by_lo) && (yc <= by_hi);
        }
        const unsigned long long m = __ballot(pred);
        if (lane == 0) s_cnt[wave] = __popcll(m);
        __syncthreads();
        const int c0 = s_cnt[0], c1 = s_cnt[1], c2 = s_cnt[2], c3 = s_cnt[3];
        int base = total;
        if (wave > 0) base += c0;
        if (wave > 1) base += c1;
        if (wave > 2) base += c2;
        if (pred) {
            const int pos = base + __popcll(m & ((1ULL << lane) - 1ULL));
            s_list[pos] = (short)n;
        }
        total += c0 + c1 + c2 + c3;
        __syncthreads();
    }
    const int M = total;

    // thread covers 1x x 4y pixels: u = x (0..15), v = y quad (0..15)
    const int u = tid >> 4;
    const int v = tid & 15;

    float acc0[4], acc1[4];
    #pragma unroll
    for (int j = 0; j < 4; ++j) { acc0[j] = 0.f; acc1[j] = 0.f; }

    // exp(-d^2/(2*32*32)) = exp2(d^2 * C2), C2 = -log2(e)/2048
    const float C2 = -1.4426950408889634f / 2048.0f;

    for (int m0 = 0; m0 < M; m0 += BATCH) {
        const int B = (M - m0 < BATCH) ? (M - m0) : BATCH;
        // ex fill: B*TX slots (<=128), threads 0..127, single pass
        if (tid < B * TX) {
            const int b = tid >> 4, r = tid & (TX - 1);
            const int n = (int)s_list[m0 + b];
            const float dx = (float)(x0 + r) - s_xc[n];
            s_ex[b][r] = EXP2F(dx * dx * C2);
        }
        // ey fill: B*TY slots (<=512 -> two passes)
        for (int s = tid; s < B * TY; s += 256) {
            const int b = s >> 6, r = s & (TY - 1);
            const int n = (int)s_list[m0 + b];
            const float dy = (float)(y0 + r) - s_yc[n];
            s_ey[b][r] = EXP2F(dy * dy * C2);
        }
        __syncthreads();

        for (int b = 0; b < B; ++b) {
            const int n = (int)s_list[m0 + b];
            const float v0 = s_v0[n], v1 = s_v1[n];
            const float exu = s_ex[b][u];
            const float4 ey4 = *reinterpret_cast<const float4*>(&s_ey[b][v * 4]);
            const float eys[4] = {ey4.x, ey4.y, ey4.z, ey4.w};
            const float e0 = exu * v0;
            const float e1 = exu * v1;
            #pragma unroll
            for (int j = 0; j < 4; ++j) {
                acc0[j] = fmaf(e0, eys[j], acc0[j]);
                acc1[j] = fmaf(e1, eys[j], acc1[j]);
            }
        }
        __syncthreads();
    }

    // out[c*W*L + x*L + y]; nontemporal f4 stores
    const size_t WL = (size_t)W * (size_t)L;
    const size_t x  = (size_t)(x0 + u);
    const int yb = y0 + v * 4;
    f4 o0 = (f4){acc0[0], acc0[1], acc0[2], acc0[3]};
    f4 o1 = (f4){acc1[0], acc1[1], acc1[2], acc1[3]};
    __builtin_nontemporal_store(o0, (f4*)&out[x * (size_t)L + (size_t)yb]);
    __builtin_nontemporal_store(o1, (f4*)&out[WL + x * (size_t)L + (size_t)yb]);
}

extern "C" void kernel_launch(void* const* d_in, const int* in_sizes, int n_in,
                              void* d_out, int out_size, void* d_ws, size_t ws_size,
                              hipStream_t stream) {
    const float* init_vectors = (const float*)d_in[0];
    const int*   x_coord      = (const int*)d_in[1];
    const int*   y_coord      = (const int*)d_in[2];
    const int*   d_width      = (const int*)d_in[3];
    const int*   d_lenth      = (const int*)d_in[4];
    float*       out          = (float*)d_out;

    const int N = in_sizes[1];                 // 512
    const int WL = out_size / 2;
    int W = 1;
    while ((long long)W * (long long)W < (long long)WL) W <<= 1;
    const int L = WL / W;                      // 2048, 2048

    dim3 grid(W / TX, L / TY);                 // 128 x 32 = 4096 blocks
    dim3 block(256);
    hipLaunchKernelGGL(motion_field_kernel, grid, block, 0, stream,
                       init_vectors, x_coord, y_coord, d_width, d_lenth,
                       out, N, W, L);
}

// Round 14
// 15.213 us; speedup vs baseline: 1.1854x; 1.1854x over previous
//
#include <hip/hip_runtime.h>
#include <math.h>

// field[c,x,y] = sum_n exp(-(x-xc[n])^2/(2s^2)) * exp(-(y-yc[n])^2/(2s^2)) * v[c,n]
// v = init_vectors * (32/(W+L)), s = 32. Output [1,2,W,L] fp32, y fastest.
//
// R13 = R12 with the fill-indexing bug fixed: R12's "else if" ey-fill branch
// was unreachable for full batches (B*TX==256 -> all threads took the ex
// branch, ey stayed poison). Now ex and ey fills are INDEPENDENT predicates
// (threads 0..B*TX-1 do ex; threads 0..B*HY-1 also do ey).
// R12 content: (1) half-tile store streaming (store half-0 mid-kernel so its
// drain overlaps half-1 compute), (2) preamble trim (scan from global,
// compact only candidates into LDS).

#define N_MAX     512
#define CAND_MAX  192
#define TX        32
#define TY        64
#define HY        32           // half-tile height in y
#define R_CUT     128.0f
#define BATCH     8

#define EXP2F(x) __builtin_amdgcn_exp2f(x)

typedef float f4 __attribute__((ext_vector_type(4)));

__global__ __launch_bounds__(256, 8) void motion_field_kernel(
    const float* __restrict__ init_vectors,  // [2, N]
    const int*   __restrict__ x_coord,       // [N]
    const int*   __restrict__ y_coord,       // [N]
    const int*   __restrict__ d_width,       // [1]
    const int*   __restrict__ d_lenth,       // [1]
    float*       __restrict__ out,           // [2, W, L]
    int N, int W, int L)
{
    __shared__ float s_cx[CAND_MAX], s_cy[CAND_MAX];
    __shared__ float s_cv0[CAND_MAX], s_cv1[CAND_MAX];
    __shared__ int   s_cnt[4];
    __shared__ float s_ex[BATCH][TX];        // 1 KB
    __shared__ float s_ey[BATCH][HY];        // 1 KB

    const int tid  = threadIdx.x;
    const int wave = tid >> 6;
    const int lane = tid & 63;

    const float scale = 32.0f / (float)(d_width[0] + d_lenth[0]);  // MAGNITUDE=1

    const int x0 = blockIdx.x * TX;
    const int y0 = blockIdx.y * TY;
    const float bx_lo = (float)x0 - R_CUT;
    const float bx_hi = (float)(x0 + TX - 1) + R_CUT;
    const float by_lo = (float)y0 - R_CUT;
    const float by_hi = (float)(y0 + TY - 1) + R_CUT;

    // ---- scan straight from global (L2-resident), compact candidates ----
    int total = 0;
    for (int base_n = 0; base_n < N; base_n += 256) {
        const int n = base_n + tid;
        bool pred = false;
        float xc = 0.f, yc = 0.f;
        if (n < N) {
            xc = (float)x_coord[n];
            yc = (float)y_coord[n];
            pred = (xc >= bx_lo) && (xc <= bx_hi) && (yc >= by_lo) && (yc <= by_hi);
        }
        const unsigned long long m = __ballot(pred);
        if (lane == 0) s_cnt[wave] = __popcll(m);
        __syncthreads();
        const int c0 = s_cnt[0], c1 = s_cnt[1], c2 = s_cnt[2], c3 = s_cnt[3];
        int base = total;
        if (wave > 0) base += c0;
        if (wave > 1) base += c1;
        if (wave > 2) base += c2;
        if (pred) {
            const int pos = base + __popcll(m & ((1ULL << lane) - 1ULL));
            if (pos < CAND_MAX) {
                s_cx[pos]  = xc;
                s_cy[pos]  = yc;
                s_cv0[pos] = init_vectors[n] * scale;
                s_cv1[pos] = init_vectors[N + n] * scale;
            }
        }
        total += c0 + c1 + c2 + c3;
        __syncthreads();
    }
    const int M = (total < CAND_MAX) ? total : CAND_MAX;

    // thread owns 1 x-row (u) x 4 y (v) within a 32x32 half-tile
    const int u = tid >> 3;          // 0..31 x row
    const int v = tid & 7;           // 0..7  y quad

    // exp(-d^2/(2*32*32)) = exp2(d^2 * C2), C2 = -log2(e)/2048
    const float C2 = -1.4426950408889634f / 2048.0f;
    const size_t WL = (size_t)W * (size_t)L;

    #pragma unroll
    for (int h = 0; h < 2; ++h) {
        const int yh = y0 + h * HY;

        float acc0[4], acc1[4];
        #pragma unroll
        for (int j = 0; j < 4; ++j) { acc0[j] = 0.f; acc1[j] = 0.f; }

        for (int m0 = 0; m0 < M; m0 += BATCH) {
            const int B = (M - m0 < BATCH) ? (M - m0) : BATCH;
            // ex fill: threads 0..B*TX-1 (<=256), one exp each
            if (tid < B * TX) {
                const int b = tid >> 5, r = tid & (TX - 1);
                const float dx = (float)(x0 + r) - s_cx[m0 + b];
                s_ex[b][r] = EXP2F(dx * dx * C2);
            }
            // ey fill: threads 0..B*HY-1 (<=256), one exp each (INDEPENDENT
            // predicate — these threads also did ex above)
            if (tid < B * HY) {
                const int b = tid >> 5, r = tid & (HY - 1);
                const float dy = (float)(yh + r) - s_cy[m0 + b];
                s_ey[b][r] = EXP2F(dy * dy * C2);
            }
            __syncthreads();

            for (int b = 0; b < B; ++b) {
                const float exu = s_ex[b][u];
                const f4 ey4 = *(const f4*)&s_ey[b][v * 4];
                const float e0 = exu * s_cv0[m0 + b];
                const float e1 = exu * s_cv1[m0 + b];
                const float eys[4] = {ey4.x, ey4.y, ey4.z, ey4.w};
                #pragma unroll
                for (int j = 0; j < 4; ++j) {
                    acc0[j] = fmaf(e0, eys[j], acc0[j]);
                    acc1[j] = fmaf(e1, eys[j], acc1[j]);
                }
            }
            __syncthreads();
        }

        // stream this half's stores now (drains under next half's compute)
        const size_t x  = (size_t)(x0 + u);
        const int yb = yh + v * 4;
        f4 o0 = (f4){acc0[0], acc0[1], acc0[2], acc0[3]};
        f4 o1 = (f4){acc1[0], acc1[1], acc1[2], acc1[3]};
        __builtin_nontemporal_store(o0, (f4*)&out[x * (size_t)L + (size_t)yb]);
        __builtin_nontemporal_store(o1, (f4*)&out[WL + x * (size_t)L + (size_t)yb]);
    }
}

extern "C" void kernel_launch(void* const* d_in, const int* in_sizes, int n_in,
                              void* d_out, int out_size, void* d_ws, size_t ws_size,
                              hipStream_t stream) {
    const float* init_vectors = (const float*)d_in[0];
    const int*   x_coord      = (const int*)d_in[1];
    const int*   y_coord      = (const int*)d_in[2];
    const int*   d_width      = (const int*)d_in[3];
    const int*   d_lenth      = (const int*)d_in[4];
    float*       out          = (float*)d_out;

    const int N = in_sizes[1];                 // 512
    const int WL = out_size / 2;
    int W = 1;
    while ((long long)W * (long long)W < (long long)WL) W <<= 1;
    const int L = WL / W;                      // 2048, 2048

    dim3 grid(W / TX, L / TY);                 // 64 x 32 = 2048 blocks
    dim3 block(256);
    hipLaunchKernelGGL(motion_field_kernel, grid, block, 0, stream,
                       init_vectors, x_coord, y_coord, d_width, d_lenth,
                       out, N, W, L);
}